// Round 1
// baseline (510.061 us; speedup 1.0000x reference)
//
#include <hip/hip_runtime.h>

#define TLEN 65536
#define XPLEN 65648   /* TLEN + 112 padded length */
#define TO 32769
#define NFILT 112
#define OU_SIZE 50333184   /* 16*32*3*32769 */
#define REM_MAX 1048608    /* 32*TO */

// ---------------- helpers ----------------
__device__ __forceinline__ float fetch_xp(const float* __restrict__ xr, int idx) {
    // xp[idx] for idx in [0, XPLEN) ; xp = symmetric-pad(x, 55 left, 57 right)
    int p = idx - 55;
    p = (p < 0) ? (-1 - p) : p;
    p = (p >= TLEN) ? (2 * TLEN - 1 - p) : p;
    return xr[p];
}

// ---------------- K1: filters ----------------
__global__ __launch_bounds__(256) void k1_filters(
    const float* __restrict__ m, const float* __restrict__ p,
    const float* __restrict__ sd, const float* __restrict__ kb,
    float* __restrict__ Wout)
{
    __shared__ float knots[32][8];
    __shared__ float yh[2][6][4];
    __shared__ float fv[2][32][112];
    __shared__ float mx[64];
    __shared__ float mv[2][7], pv[2][7];
    int tid = threadIdx.x;
    if (tid < 32) {
        float s = exp2f((float)tid * 0.125f) + sd[tid];
        float cum = 0.f;
        for (int k = 0; k < 7; ++k) {
            float c = fminf(fmaxf(kb[k] * s, 1.f), 105.f);
            knots[tid][k] = cum - 3.f * s;   // exclusive cumsum - (K//2)*scale
            cum += c;
        }
    }
    if (tid < 2) {
        float mean = 0.f;
        for (int k = 1; k <= 5; ++k) mean += m[tid * 7 + k];
        mean *= 0.2f;
        for (int k = 0; k < 7; ++k) {
            float msk = (k == 0 || k == 6) ? 0.f : 1.f;
            mv[tid][k] = (m[tid * 7 + k] - mean) * msk;
            pv[tid][k] = p[tid * 7 + k] * msk;
        }
    }
    __syncthreads();
    if (tid < 12) {
        int i = tid / 6, kk = tid % 6;
        float y0 = mv[i][kk], y1 = mv[i][kk + 1], y2 = pv[i][kk], y3 = pv[i][kk + 1];
        // einsum with h = [[1,0,-3,2],[0,1,-2,1],[0,0,3,-2],[0,0,-1,1]]
        yh[i][kk][0] = y0;
        yh[i][kk][1] = y1;
        yh[i][kk][2] = -3.f * y0 - 2.f * y1 + 3.f * y2 - y3;
        yh[i][kk][3] = 2.f * y0 + y1 - 2.f * y2 + y3;
    }
    __syncthreads();
    for (int idx = tid; idx < 7168; idx += 256) {
        int i = idx / 3584, s = (idx / 112) % 32, fi = idx % 112;
        float xi = -56.f + (float)fi * (112.f / 111.f);
        float val = 0.f;
        for (int kk = 0; kk < 6; ++kk) {
            float x0 = knots[s][kk], x1 = knots[s][kk + 1];
            float xn = (xi - x0) / (x1 - x0);
            if (xn >= 0.f && xn < 1.f) {
                val += ((yh[i][kk][3] * xn + yh[i][kk][2]) * xn + yh[i][kk][1]) * xn + yh[i][kk][0];
            }
        }
        fv[i][s][fi] = val;
    }
    __syncthreads();
    if (tid < 64) {
        int i = tid >> 5, s = tid & 31;
        float mm_ = -1e30f;
        for (int fi = 0; fi < 112; ++fi) mm_ = fmaxf(mm_, fv[i][s][fi]);
        mx[tid] = mm_;
    }
    __syncthreads();
    for (int idx = tid; idx < 7168; idx += 256) {
        int i = idx / 3584, s = (idx / 112) % 32, fi = idx % 112;
        int o = i * 32 + s;
        Wout[fi * 64 + o] = fv[i][s][fi] / mx[o];   // layout W[k][o]
    }
}

// ---------------- K1b: A[j][k] = sum_o W[j,o] W[k,o] ----------------
__global__ __launch_bounds__(256) void k1b_A(const float* __restrict__ W, float* __restrict__ A)
{
    int idx = blockIdx.x * 256 + threadIdx.x;
    if (idx >= 12544) return;
    int j = idx / 112, k = idx % 112;
    float s = 0.f;
    for (int o = 0; o < 64; ++o) s += W[j * 64 + o] * W[k * 64 + o];
    A[idx] = s;
}

// ---------------- K1c: C[q][dd] (dd = d+111, 224 entries, last = 0) ----------------
__global__ __launch_bounds__(256) void k1c_C(const float* __restrict__ A, float* __restrict__ C)
{
    int idx = blockIdx.x * 256 + threadIdx.x;
    if (idx >= 448) return;
    int q = idx / 224, dd = idx % 224;
    int d = dd - 111;
    float s = 0.f;
    for (int k = q; k < 112; k += 2) {
        int jj = k + d;
        if (jj >= 0 && jj < 112) s += A[jj * 112 + k];
    }
    C[idx] = s;
}

// ---------------- K2: forward conv + modulus + pooling ----------------
__global__ __launch_bounds__(256) void k2_fwd(
    const float* __restrict__ x, const float* __restrict__ W,
    float* __restrict__ out_u, float* __restrict__ out_s)
{
    __shared__ __align__(16) float se[120];
    __shared__ __align__(16) float so[120];
    __shared__ float xch[64][65];
    __shared__ float ub[32][65];
    int row = blockIdx.y;                 // n = b*3 + c
    int b = row / 3, c = row % 3;
    int t0 = blockIdx.x * 64;
    const float* xr = x + row * TLEN;
    int tid = threadIdx.x;

    if (tid < 238) {
        int idx = 2 * t0 + tid;
        float v = 0.f;
        if (idx < XPLEN) v = fetch_xp(xr, idx);
        if (tid & 1) so[tid >> 1] = v; else se[tid >> 1] = v;
    }
    __syncthreads();

    int tl = tid & 63;
    int og = tid >> 6;
    int og16 = __builtin_amdgcn_readfirstlane(og * 16);
    const float* Wp = W + og16;

    float acc[16];
#pragma unroll
    for (int oi = 0; oi < 16; ++oi) acc[oi] = 0.f;

    for (int j = 0; j < 56; ++j) {
        float a = se[tl + j];
        float bq = so[tl + j];
        const float4* w0 = (const float4*)(Wp + (2 * j) * 64);
        const float4* w1 = (const float4*)(Wp + (2 * j + 1) * 64);
        float4 wa0 = w0[0], wa1 = w0[1], wa2 = w0[2], wa3 = w0[3];
        float4 wb0 = w1[0], wb1 = w1[1], wb2 = w1[2], wb3 = w1[3];
        acc[0]  = fmaf(a, wa0.x, fmaf(bq, wb0.x, acc[0]));
        acc[1]  = fmaf(a, wa0.y, fmaf(bq, wb0.y, acc[1]));
        acc[2]  = fmaf(a, wa0.z, fmaf(bq, wb0.z, acc[2]));
        acc[3]  = fmaf(a, wa0.w, fmaf(bq, wb0.w, acc[3]));
        acc[4]  = fmaf(a, wa1.x, fmaf(bq, wb1.x, acc[4]));
        acc[5]  = fmaf(a, wa1.y, fmaf(bq, wb1.y, acc[5]));
        acc[6]  = fmaf(a, wa1.z, fmaf(bq, wb1.z, acc[6]));
        acc[7]  = fmaf(a, wa1.w, fmaf(bq, wb1.w, acc[7]));
        acc[8]  = fmaf(a, wa2.x, fmaf(bq, wb2.x, acc[8]));
        acc[9]  = fmaf(a, wa2.y, fmaf(bq, wb2.y, acc[9]));
        acc[10] = fmaf(a, wa2.z, fmaf(bq, wb2.z, acc[10]));
        acc[11] = fmaf(a, wa2.w, fmaf(bq, wb2.w, acc[11]));
        acc[12] = fmaf(a, wa3.x, fmaf(bq, wb3.x, acc[12]));
        acc[13] = fmaf(a, wa3.y, fmaf(bq, wb3.y, acc[13]));
        acc[14] = fmaf(a, wa3.z, fmaf(bq, wb3.z, acc[14]));
        acc[15] = fmaf(a, wa3.w, fmaf(bq, wb3.w, acc[15]));
    }
#pragma unroll
    for (int oi = 0; oi < 16; ++oi) xch[og * 16 + oi][tl] = acc[oi];
    __syncthreads();

    // modulus phase: iterate the block's contiguous rem-range [t0*32, t0*32+2048)
    int rembase = t0 * 32;
#pragma unroll
    for (int r = 0; r < 8; ++r) {
        int rem = rembase + tid + 256 * r;
        if (rem < REM_MAX) {
            int k = rem / TO;
            int tt = rem - k * TO;
            int sc = rem & 31;
            int tloc = (rem >> 5) - t0;
            float re = xch[sc][tloc];
            float im = xch[sc + 32][tloc];
            float u = sqrtf(re * re + im * im);
            out_u[((b * 32 + k) * 3 + c) * TO + tt] = u;
            ub[sc][tloc] = u;
        }
    }
    __syncthreads();

    int tpbase = t0 >> 2;
#pragma unroll
    for (int r = 0; r < 2; ++r) {
        int idx = tid + 256 * r;
        int sc = idx >> 4, tp = idx & 15;
        if (tpbase + tp < 8192) {
            float sum = ub[sc][tp * 4] + ub[sc][tp * 4 + 1] + ub[sc][tp * 4 + 2] + ub[sc][tp * 4 + 3];
            out_s[(row * 32 + sc) * 8192 + tpbase + tp] = sum * 0.25f;
        }
    }
}

// ---------------- K3: interior inverse via combined correlation + loss ----------------
__global__ __launch_bounds__(256) void k3_interior(
    const float* __restrict__ x, const float* __restrict__ C,
    double* __restrict__ loss_acc)
{
    __shared__ __align__(16) float sx[1248];
    int row = blockIdx.y;
    int s0 = 56 + blockIdx.x * 1024;
    const float* xr = x + row * TLEN;
    for (int li = threadIdx.x; li < 1248; li += 256) {
        int pp = s0 - 111 + li;
        pp = (pp < 0) ? (-1 - pp) : pp;
        pp = (pp >= TLEN) ? (2 * TLEN - 1 - pp) : pp;
        sx[li] = xr[pp];
    }
    __syncthreads();

    int qe = (55 + s0) & 1;
    const float* Ce = C + qe * 224;
    const float* Co = C + (qe ^ 1) * 224;
    int base = threadIdx.x * 4;
    float a0 = 0.f, a1 = 0.f, a2 = 0.f, a3 = 0.f;
    float4 cur = *(const float4*)&sx[base];
#pragma unroll 4
    for (int d4 = 0; d4 < 56; ++d4) {
        float4 nxt = *(const float4*)&sx[base + 4 * d4 + 4];
        int ci = 4 * d4;
        float ce0 = Ce[ci],     co0 = Co[ci];
        float ce1 = Ce[ci + 1], co1 = Co[ci + 1];
        float ce2 = Ce[ci + 2], co2 = Co[ci + 2];
        float ce3 = Ce[ci + 3], co3 = Co[ci + 3];
        a0 = fmaf(cur.x, ce0, a0); a1 = fmaf(cur.y, co0, a1); a2 = fmaf(cur.z, ce0, a2); a3 = fmaf(cur.w, co0, a3);
        a0 = fmaf(cur.y, ce1, a0); a1 = fmaf(cur.z, co1, a1); a2 = fmaf(cur.w, ce1, a2); a3 = fmaf(nxt.x, co1, a3);
        a0 = fmaf(cur.z, ce2, a0); a1 = fmaf(cur.w, co2, a1); a2 = fmaf(nxt.x, ce2, a2); a3 = fmaf(nxt.y, co2, a3);
        a0 = fmaf(cur.w, ce3, a0); a1 = fmaf(nxt.x, co3, a1); a2 = fmaf(nxt.y, ce3, a2); a3 = fmaf(nxt.z, co3, a3);
        cur = nxt;
    }

    int sb = s0 + base;
    double lsum = 0.0;
    if (sb + 0 <= 65478) { float d = a0 - sx[base + 111]; lsum += (double)d * d; }
    if (sb + 1 <= 65478) { float d = a1 - sx[base + 112]; lsum += (double)d * d; }
    if (sb + 2 <= 65478) { float d = a2 - sx[base + 113]; lsum += (double)d * d; }
    if (sb + 3 <= 65478) { float d = a3 - sx[base + 114]; lsum += (double)d * d; }
    for (int off = 32; off > 0; off >>= 1) lsum += __shfl_down(lsum, off, 64);
    if ((threadIdx.x & 63) == 0) atomicAdd(loss_acc, lsum);
}

// ---------------- K4: edge g_xp evals (one wave each) ----------------
__global__ __launch_bounds__(256) void k4_edge(
    const float* __restrict__ x, const float* __restrict__ A,
    float* __restrict__ edge)
{
    __shared__ float Al[112 * 113];
    for (int idx = threadIdx.x; idx < 12544; idx += 256)
        Al[(idx / 112) * 113 + (idx % 112)] = A[idx];
    __syncthreads();

    int w = blockIdx.x * 4 + (threadIdx.x >> 6);
    int lane = threadIdx.x & 63;
    if (w >= 10800) return;
    int row = w / 225, e = w % 225;
    int i, sidx, side;
    if (e < 111) {
        side = 0;
        if (e < 56) { sidx = e; i = 55 + e; }
        else        { sidx = e - 56; i = 54 - sidx; }
    } else {
        side = 1; int er = e - 111;
        if (er < 57) { sidx = er; i = 65534 + er; }
        else         { sidx = er - 57; i = 65647 - sidx; }
    }
    const float* xr = x + row * TLEN;
    int klo = max(0, i - 65536);
    int khi = min(111, i);
    int k0 = klo + ((klo ^ i) & 1);
    float part = 0.f;
    for (int k = k0; k <= khi; k += 2) {
        int basei = i - k;
        part = fmaf(fetch_xp(xr, basei + lane), Al[lane * 113 + k], part);
        if (lane < 48)
            part = fmaf(fetch_xp(xr, basei + 64 + lane), Al[(lane + 64) * 113 + k], part);
    }
    for (int off = 32; off > 0; off >>= 1) part += __shfl_down(part, off, 64);
    if (lane == 0) atomicAdd(&edge[row * 128 + side * 64 + sidx], part);
}

// ---------------- K5: edge loss + finalize ----------------
__global__ __launch_bounds__(256) void k5_final(
    const float* __restrict__ x, const float* __restrict__ edge,
    const double* __restrict__ loss_acc, float* __restrict__ out_loss)
{
    __shared__ double red[256];
    double acc = 0.0;
    for (int idx = threadIdx.x; idx < 5424; idx += 256) {
        int row = idx / 113, r = idx % 113;
        int s, slot;
        if (r < 56) { s = r; slot = row * 128 + r; }
        else        { s = 65479 + (r - 56); slot = row * 128 + 64 + (r - 56); }
        float diff = edge[slot] - x[row * TLEN + s];
        acc += (double)diff * diff;
    }
    red[threadIdx.x] = acc;
    __syncthreads();
    for (int st = 128; st > 0; st >>= 1) {
        if (threadIdx.x < st) red[threadIdx.x] += red[threadIdx.x + st];
        __syncthreads();
    }
    if (threadIdx.x == 0)
        out_loss[0] = (float)((red[0] + loss_acc[0]) / 3145728.0);
}

// ---------------- launch ----------------
extern "C" void kernel_launch(void* const* d_in, const int* in_sizes, int n_in,
                              void* d_out, int out_size, void* d_ws, size_t ws_size,
                              hipStream_t stream)
{
    (void)in_sizes; (void)n_in; (void)ws_size;
    const float* x  = (const float*)d_in[0];
    const float* m  = (const float*)d_in[1];
    const float* p  = (const float*)d_in[2];
    const float* sd = (const float*)d_in[3];
    const float* kb = (const float*)d_in[4];
    float* out = (float*)d_out;
    float* ws  = (float*)d_ws;

    float* ws_w    = ws;            // 7168 : W[k][o]
    float* ws_C    = ws + 7168;     // 448  : C[q][224]
    float* ws_A    = ws + 7616;     // 12544: A[j][k]
    float* ws_edge = ws + 20160;    // 6144 : edge inverse accum
    double* ws_loss = (double*)(ws + 26304); // interior loss accum (double)

    // zero the accumulators (edge buffer + loss) every launch
    hipMemsetAsync(ws + 20160, 0, (6144 + 2) * sizeof(float), stream);

    k1_filters<<<1, 256, 0, stream>>>(m, p, sd, kb, ws_w);
    k1b_A<<<49, 256, 0, stream>>>(ws_w, ws_A);
    k1c_C<<<2, 256, 0, stream>>>(ws_A, ws_C);
    k2_fwd<<<dim3(513, 48), 256, 0, stream>>>(x, ws_w, out, out + OU_SIZE);
    k3_interior<<<dim3(64, 48), 256, 0, stream>>>(x, ws_C, ws_loss);
    k4_edge<<<2700, 256, 0, stream>>>(x, ws_A, ws_edge);
    k5_final<<<1, 256, 0, stream>>>(x, ws_edge, ws_loss, out + (out_size - 1));
}

// Round 2
// 428.493 us; speedup vs baseline: 1.1904x; 1.1904x over previous
//
#include <hip/hip_runtime.h>

#define TLEN 65536
#define XPLEN 65648   /* TLEN + 112 padded length */
#define TO 32769
#define OU_SIZE 50333184   /* 16*32*3*32769 */
#define REM_MAX 1048608    /* 32*TO */

typedef __attribute__((ext_vector_type(8))) short short8v;
typedef __attribute__((ext_vector_type(4))) float float4v;

// ---------------- helpers ----------------
__device__ __forceinline__ float fetch_xp(const float* __restrict__ xr, int idx) {
    // xp[idx] for idx in [0, XPLEN) ; xp = symmetric-pad(x, 55 left, 57 right)
    int p = idx - 55;
    p = (p < 0) ? (-1 - p) : p;
    p = (p >= TLEN) ? (2 * TLEN - 1 - p) : p;
    return xr[p];
}

__device__ __forceinline__ ushort f2bf(float f) {
    unsigned u = __float_as_uint(f);
    unsigned r = (u + 0x7fffu + ((u >> 16) & 1u)) >> 16;
    return (ushort)r;
}

// ---------------- K1: filters ----------------
__global__ __launch_bounds__(256) void k1_filters(
    const float* __restrict__ m, const float* __restrict__ p,
    const float* __restrict__ sd, const float* __restrict__ kb,
    float* __restrict__ Wout, ushort* __restrict__ Wtb)
{
    __shared__ float knots[32][8];
    __shared__ float yh[2][6][4];
    __shared__ float fv[2][32][112];
    __shared__ float mx[64];
    __shared__ float mv[2][7], pv[2][7];
    int tid = threadIdx.x;
    if (tid < 32) {
        float s = exp2f((float)tid * 0.125f) + sd[tid];
        float cum = 0.f;
        for (int k = 0; k < 7; ++k) {
            float c = fminf(fmaxf(kb[k] * s, 1.f), 105.f);
            knots[tid][k] = cum - 3.f * s;   // exclusive cumsum - (K//2)*scale
            cum += c;
        }
    }
    if (tid < 2) {
        float mean = 0.f;
        for (int k = 1; k <= 5; ++k) mean += m[tid * 7 + k];
        mean *= 0.2f;
        for (int k = 0; k < 7; ++k) {
            float msk = (k == 0 || k == 6) ? 0.f : 1.f;
            mv[tid][k] = (m[tid * 7 + k] - mean) * msk;
            pv[tid][k] = p[tid * 7 + k] * msk;
        }
    }
    __syncthreads();
    if (tid < 12) {
        int i = tid / 6, kk = tid % 6;
        float y0 = mv[i][kk], y1 = mv[i][kk + 1], y2 = pv[i][kk], y3 = pv[i][kk + 1];
        yh[i][kk][0] = y0;
        yh[i][kk][1] = y1;
        yh[i][kk][2] = -3.f * y0 - 2.f * y1 + 3.f * y2 - y3;
        yh[i][kk][3] = 2.f * y0 + y1 - 2.f * y2 + y3;
    }
    __syncthreads();
    for (int idx = tid; idx < 7168; idx += 256) {
        int i = idx / 3584, s = (idx / 112) % 32, fi = idx % 112;
        float xi = -56.f + (float)fi * (112.f / 111.f);
        float val = 0.f;
        for (int kk = 0; kk < 6; ++kk) {
            float x0 = knots[s][kk], x1 = knots[s][kk + 1];
            float xn = (xi - x0) / (x1 - x0);
            if (xn >= 0.f && xn < 1.f) {
                val += ((yh[i][kk][3] * xn + yh[i][kk][2]) * xn + yh[i][kk][1]) * xn + yh[i][kk][0];
            }
        }
        fv[i][s][fi] = val;
    }
    __syncthreads();
    if (tid < 64) {
        int i = tid >> 5, s = tid & 31;
        float mm_ = -1e30f;
        for (int fi = 0; fi < 112; ++fi) mm_ = fmaxf(mm_, fv[i][s][fi]);
        mx[tid] = mm_;
    }
    __syncthreads();
    for (int idx = tid; idx < 7168; idx += 256) {
        int i = idx / 3584, s = (idx / 112) % 32, fi = idx % 112;
        int o = i * 32 + s;
        Wout[fi * 64 + o] = fv[i][s][fi] / mx[o];   // layout W[k][o] (f32, for A)
    }
    for (int idx = tid; idx < 8192; idx += 256) {
        int o = idx >> 7, k = idx & 127;
        float val = (k < 112) ? fv[o >> 5][o & 31][k] / mx[o] : 0.f;
        Wtb[idx] = f2bf(val);                      // layout Wt[o][k] bf16, K padded to 128
    }
}

// ---------------- K1b: A[j][k] = sum_o W[j,o] W[k,o] ----------------
__global__ __launch_bounds__(256) void k1b_A(const float* __restrict__ W, float* __restrict__ A)
{
    int idx = blockIdx.x * 256 + threadIdx.x;
    if (idx >= 12544) return;
    int j = idx / 112, k = idx % 112;
    float s = 0.f;
    for (int o = 0; o < 64; ++o) s += W[j * 64 + o] * W[k * 64 + o];
    A[idx] = s;
}

// ---------------- K1c: C[q][dd] ----------------
__global__ __launch_bounds__(256) void k1c_C(const float* __restrict__ A, float* __restrict__ C)
{
    int idx = blockIdx.x * 256 + threadIdx.x;
    if (idx >= 448) return;
    int q = idx / 224, dd = idx % 224;
    int d = dd - 111;
    float s = 0.f;
    for (int k = q; k < 112; k += 2) {
        int jj = k + d;
        if (jj >= 0 && jj < 112) s += A[jj * 112 + k];
    }
    C[idx] = s;
}

// ---------------- K2: MFMA conv + modulus + pooling ----------------
__global__ __launch_bounds__(256) void k2_fwd(
    const float* __restrict__ x, const ushort* __restrict__ Wtb,
    float* __restrict__ out_u, float* __restrict__ out_s)
{
    __shared__ __align__(16) ushort xraw[256];   // bf16 window xp[2*t0 .. 2*t0+255]
    __shared__ float xch[64][65];                // conv result [o][t_local]
    __shared__ float ub[32][65];
    int row = blockIdx.y;                 // n = b*3 + c
    int b = row / 3, c = row % 3;
    int t0 = blockIdx.x * 64;
    const float* xr = x + row * TLEN;
    int tid = threadIdx.x;

    {
        int idx = 2 * t0 + tid;
        float v = (idx < XPLEN) ? fetch_xp(xr, idx) : 0.f;
        xraw[tid] = f2bf(v);
    }
    __syncthreads();

    int l = tid & 63, w = tid >> 6;
    int wm = w >> 1, wn = w & 1;
    int r16 = l & 15, kg = l >> 4;

    float4v acc00 = {0.f, 0.f, 0.f, 0.f};
    float4v acc01 = {0.f, 0.f, 0.f, 0.f};
    float4v acc10 = {0.f, 0.f, 0.f, 0.f};
    float4v acc11 = {0.f, 0.f, 0.f, 0.f};

    const ushort* Wb = Wtb + (wn * 32 + r16) * 128 + kg * 8;
    int abase = 64 * wm + 2 * r16 + 8 * kg;

    union U8 { short8v v; uint u[4]; uint4 q; };

#pragma unroll
    for (int ks = 0; ks < 4; ++ks) {
        U8 b0, b1, a0, a1;
        b0.q = *(const uint4*)(Wb + ks * 32);          // fn=0
        b1.q = *(const uint4*)(Wb + 2048 + ks * 32);   // fn=1 (o+16)
        int e0 = abase + ks * 32;
#pragma unroll
        for (int q = 0; q < 4; ++q) {
            a0.u[q] = *(const uint*)&xraw[e0 + 2 * q];        // fm=0
            a1.u[q] = *(const uint*)&xraw[e0 + 32 + 2 * q];   // fm=1 (t+16)
        }
        acc00 = __builtin_amdgcn_mfma_f32_16x16x32_bf16(a0.v, b0.v, acc00, 0, 0, 0);
        acc01 = __builtin_amdgcn_mfma_f32_16x16x32_bf16(a0.v, b1.v, acc01, 0, 0, 0);
        acc10 = __builtin_amdgcn_mfma_f32_16x16x32_bf16(a1.v, b0.v, acc10, 0, 0, 0);
        acc11 = __builtin_amdgcn_mfma_f32_16x16x32_bf16(a1.v, b1.v, acc11, 0, 0, 0);
    }

    // C/D layout: col(o) = lane&15, row(t) = (lane>>4)*4 + reg
    {
        int ob = wn * 32 + r16;
        int tb = wm * 32 + 4 * kg;
#pragma unroll
        for (int r = 0; r < 4; ++r) {
            xch[ob][tb + r]           = acc00[r];
            xch[ob + 16][tb + r]      = acc01[r];
            xch[ob][tb + 16 + r]      = acc10[r];
            xch[ob + 16][tb + 16 + r] = acc11[r];
        }
    }
    __syncthreads();

    // modulus phase
    int rembase = t0 * 32;
#pragma unroll
    for (int r = 0; r < 8; ++r) {
        int rem = rembase + tid + 256 * r;
        if (rem < REM_MAX) {
            int k = rem / TO;
            int tt = rem - k * TO;
            int sc = rem & 31;
            int tloc = (rem >> 5) - t0;
            float re = xch[sc][tloc];
            float im = xch[sc + 32][tloc];
            float u = sqrtf(re * re + im * im);
            out_u[((b * 32 + k) * 3 + c) * TO + tt] = u;
            ub[sc][tloc] = u;
        }
    }
    __syncthreads();

    int tpbase = t0 >> 2;
#pragma unroll
    for (int r = 0; r < 2; ++r) {
        int idx = tid + 256 * r;
        int sc = idx >> 4, tp = idx & 15;
        if (tpbase + tp < 8192) {
            float sum = ub[sc][tp * 4] + ub[sc][tp * 4 + 1] + ub[sc][tp * 4 + 2] + ub[sc][tp * 4 + 3];
            out_s[(row * 32 + sc) * 8192 + tpbase + tp] = sum * 0.25f;
        }
    }
}

// ---------------- K3: interior inverse + loss ----------------
__global__ __launch_bounds__(256) void k3_interior(
    const float* __restrict__ x, const float* __restrict__ C,
    double* __restrict__ loss_acc)
{
    __shared__ __align__(16) float sx[1248];
    int row = blockIdx.y;
    int s0 = 56 + blockIdx.x * 1024;
    const float* xr = x + row * TLEN;
    for (int li = threadIdx.x; li < 1248; li += 256) {
        int pp = s0 - 111 + li;
        pp = (pp < 0) ? (-1 - pp) : pp;
        pp = (pp >= TLEN) ? (2 * TLEN - 1 - pp) : pp;
        sx[li] = xr[pp];
    }
    __syncthreads();

    int qe = (55 + s0) & 1;
    const float* Ce = C + qe * 224;
    const float* Co = C + (qe ^ 1) * 224;
    int base = threadIdx.x * 4;
    float a0 = 0.f, a1 = 0.f, a2 = 0.f, a3 = 0.f;
    float4 cur = *(const float4*)&sx[base];
#pragma unroll 4
    for (int d4 = 0; d4 < 56; ++d4) {
        float4 nxt = *(const float4*)&sx[base + 4 * d4 + 4];
        int ci = 4 * d4;
        float ce0 = Ce[ci],     co0 = Co[ci];
        float ce1 = Ce[ci + 1], co1 = Co[ci + 1];
        float ce2 = Ce[ci + 2], co2 = Co[ci + 2];
        float ce3 = Ce[ci + 3], co3 = Co[ci + 3];
        a0 = fmaf(cur.x, ce0, a0); a1 = fmaf(cur.y, co0, a1); a2 = fmaf(cur.z, ce0, a2); a3 = fmaf(cur.w, co0, a3);
        a0 = fmaf(cur.y, ce1, a0); a1 = fmaf(cur.z, co1, a1); a2 = fmaf(cur.w, ce1, a2); a3 = fmaf(nxt.x, co1, a3);
        a0 = fmaf(cur.z, ce2, a0); a1 = fmaf(cur.w, co2, a1); a2 = fmaf(nxt.x, ce2, a2); a3 = fmaf(nxt.y, co2, a3);
        a0 = fmaf(cur.w, ce3, a0); a1 = fmaf(nxt.x, co3, a1); a2 = fmaf(nxt.y, ce3, a2); a3 = fmaf(nxt.z, co3, a3);
        cur = nxt;
    }

    int sb = s0 + base;
    double lsum = 0.0;
    if (sb + 0 <= 65478) { float d = a0 - sx[base + 111]; lsum += (double)d * d; }
    if (sb + 1 <= 65478) { float d = a1 - sx[base + 112]; lsum += (double)d * d; }
    if (sb + 2 <= 65478) { float d = a2 - sx[base + 113]; lsum += (double)d * d; }
    if (sb + 3 <= 65478) { float d = a3 - sx[base + 114]; lsum += (double)d * d; }
    for (int off = 32; off > 0; off >>= 1) lsum += __shfl_down(lsum, off, 64);
    if ((threadIdx.x & 63) == 0) atomicAdd(loss_acc, lsum);
}

// ---------------- K4: edge g_xp evals (row x side blocks, all-LDS) ----------------
__global__ __launch_bounds__(256) void k4_edge(
    const float* __restrict__ x, const float* __restrict__ A,
    float* __restrict__ edge)
{
    __shared__ float Al[112][113];
    __shared__ float xpw[240];
    int row = blockIdx.x >> 1;
    int side = blockIdx.x & 1;
    const float* xr = x + row * TLEN;
    int tid = threadIdx.x;

    for (int idx = tid; idx < 12544; idx += 256)
        Al[idx / 112][idx % 112] = A[idx];
    {
        int n_x = side ? 225 : 222;
        int woff = side ? 65423 : 0;
        if (tid < n_x) xpw[tid] = fetch_xp(xr, woff + tid);
    }
    __syncthreads();

    int w = tid >> 6, lane = tid & 63;
    int n_e = side ? 114 : 111;
    int woff = side ? 65423 : 0;
    for (int e = w; e < n_e; e += 4) {
        int i, sidx;
        if (!side) {
            if (e < 56) { sidx = e; i = 55 + e; }
            else        { sidx = e - 56; i = 54 - sidx; }
        } else {
            if (e < 57) { sidx = e; i = 65534 + e; }
            else        { sidx = e - 57; i = 65647 - sidx; }
        }
        int klo = max(0, i - 65536);
        int khi = min(111, i);
        int k0 = klo + ((klo ^ i) & 1);
        float part = 0.f;
        for (int k = k0; k <= khi; k += 2) {
            int bi = i - k - woff;
            part = fmaf(xpw[bi + lane], Al[lane][k], part);
            if (lane < 48)
                part = fmaf(xpw[bi + 64 + lane], Al[lane + 64][k], part);
        }
        for (int off = 32; off > 0; off >>= 1) part += __shfl_down(part, off, 64);
        if (lane == 0) atomicAdd(&edge[row * 128 + side * 64 + sidx], part);
    }
}

// ---------------- K5: edge loss + finalize ----------------
__global__ __launch_bounds__(256) void k5_final(
    const float* __restrict__ x, const float* __restrict__ edge,
    const double* __restrict__ loss_acc, float* __restrict__ out_loss)
{
    __shared__ double red[256];
    double acc = 0.0;
    for (int idx = threadIdx.x; idx < 5424; idx += 256) {
        int row = idx / 113, r = idx % 113;
        int s, slot;
        if (r < 56) { s = r; slot = row * 128 + r; }
        else        { s = 65479 + (r - 56); slot = row * 128 + 64 + (r - 56); }
        float diff = edge[slot] - x[row * TLEN + s];
        acc += (double)diff * diff;
    }
    red[threadIdx.x] = acc;
    __syncthreads();
    for (int st = 128; st > 0; st >>= 1) {
        if (threadIdx.x < st) red[threadIdx.x] += red[threadIdx.x + st];
        __syncthreads();
    }
    if (threadIdx.x == 0)
        out_loss[0] = (float)((red[0] + loss_acc[0]) / 3145728.0);
}

// ---------------- launch ----------------
extern "C" void kernel_launch(void* const* d_in, const int* in_sizes, int n_in,
                              void* d_out, int out_size, void* d_ws, size_t ws_size,
                              hipStream_t stream)
{
    (void)in_sizes; (void)n_in; (void)ws_size;
    const float* x  = (const float*)d_in[0];
    const float* m  = (const float*)d_in[1];
    const float* p  = (const float*)d_in[2];
    const float* sd = (const float*)d_in[3];
    const float* kb = (const float*)d_in[4];
    float* out = (float*)d_out;
    float* ws  = (float*)d_ws;

    float* ws_w    = ws;            // 7168 : W[k][o] f32
    float* ws_C    = ws + 7168;     // 448  : C[q][224]
    float* ws_A    = ws + 7616;     // 12544: A[j][k]
    float* ws_edge = ws + 20160;    // 6144 : edge inverse accum
    double* ws_loss = (double*)(ws + 26304); // interior loss accum (double x1 + pad)
    ushort* ws_wtb = (ushort*)(ws + 26308);  // 8192 ushort: Wt[o][k] bf16 padded

    hipMemsetAsync(ws + 20160, 0, (6144 + 4) * sizeof(float), stream);

    k1_filters<<<1, 256, 0, stream>>>(m, p, sd, kb, ws_w, ws_wtb);
    k1b_A<<<49, 256, 0, stream>>>(ws_w, ws_A);
    k1c_C<<<2, 256, 0, stream>>>(ws_A, ws_C);
    k2_fwd<<<dim3(513, 48), 256, 0, stream>>>(x, ws_wtb, out, out + OU_SIZE);
    k3_interior<<<dim3(64, 48), 256, 0, stream>>>(x, ws_C, ws_loss);
    k4_edge<<<96, 256, 0, stream>>>(x, ws_A, ws_edge);
    k5_final<<<1, 256, 0, stream>>>(x, ws_edge, ws_loss, out + (out_size - 1));
}

// Round 3
// 305.349 us; speedup vs baseline: 1.6704x; 1.4033x over previous
//
#include <hip/hip_runtime.h>

#define TLEN 65536
#define XPLEN 65648   /* TLEN + 112 padded length */
#define TO 32769
#define OU_SIZE 50333184   /* 16*32*3*32769 */
#define REM_MAX 1048608    /* 32*TO */

typedef __attribute__((ext_vector_type(8))) short short8v;
typedef __attribute__((ext_vector_type(4))) float float4v;

// ---------------- helpers ----------------
__device__ __forceinline__ float fetch_xp(const float* __restrict__ xr, int idx) {
    // xp[idx] for idx in [0, XPLEN) ; xp = symmetric-pad(x, 55 left, 57 right)
    int p = idx - 55;
    p = (p < 0) ? (-1 - p) : p;
    p = (p >= TLEN) ? (2 * TLEN - 1 - p) : p;
    return xr[p];
}

__device__ __forceinline__ ushort f2bf(float f) {
    unsigned u = __float_as_uint(f);
    unsigned r = (u + 0x7fffu + ((u >> 16) & 1u)) >> 16;
    return (ushort)r;
}

// ---------------- K1: filters ----------------
__global__ __launch_bounds__(256) void k1_filters(
    const float* __restrict__ m, const float* __restrict__ p,
    const float* __restrict__ sd, const float* __restrict__ kb,
    float* __restrict__ Wout, ushort* __restrict__ Wtb)
{
    __shared__ float knots[32][8];
    __shared__ float yh[2][6][4];
    __shared__ float fv[2][32][112];
    __shared__ float mx[64];
    __shared__ float mv[2][7], pv[2][7];
    int tid = threadIdx.x;
    if (tid < 32) {
        float s = exp2f((float)tid * 0.125f) + sd[tid];
        float cum = 0.f;
        for (int k = 0; k < 7; ++k) {
            float c = fminf(fmaxf(kb[k] * s, 1.f), 105.f);
            knots[tid][k] = cum - 3.f * s;   // exclusive cumsum - (K//2)*scale
            cum += c;
        }
    }
    if (tid < 2) {
        float mean = 0.f;
        for (int k = 1; k <= 5; ++k) mean += m[tid * 7 + k];
        mean *= 0.2f;
        for (int k = 0; k < 7; ++k) {
            float msk = (k == 0 || k == 6) ? 0.f : 1.f;
            mv[tid][k] = (m[tid * 7 + k] - mean) * msk;
            pv[tid][k] = p[tid * 7 + k] * msk;
        }
    }
    __syncthreads();
    if (tid < 12) {
        int i = tid / 6, kk = tid % 6;
        float y0 = mv[i][kk], y1 = mv[i][kk + 1], y2 = pv[i][kk], y3 = pv[i][kk + 1];
        yh[i][kk][0] = y0;
        yh[i][kk][1] = y1;
        yh[i][kk][2] = -3.f * y0 - 2.f * y1 + 3.f * y2 - y3;
        yh[i][kk][3] = 2.f * y0 + y1 - 2.f * y2 + y3;
    }
    __syncthreads();
    for (int idx = tid; idx < 7168; idx += 256) {
        int i = idx / 3584, s = (idx / 112) % 32, fi = idx % 112;
        float xi = -56.f + (float)fi * (112.f / 111.f);
        float val = 0.f;
        for (int kk = 0; kk < 6; ++kk) {
            float x0 = knots[s][kk], x1 = knots[s][kk + 1];
            float xn = (xi - x0) / (x1 - x0);
            if (xn >= 0.f && xn < 1.f) {
                val += ((yh[i][kk][3] * xn + yh[i][kk][2]) * xn + yh[i][kk][1]) * xn + yh[i][kk][0];
            }
        }
        fv[i][s][fi] = val;
    }
    __syncthreads();
    if (tid < 64) {
        int i = tid >> 5, s = tid & 31;
        float mm_ = -1e30f;
        for (int fi = 0; fi < 112; ++fi) mm_ = fmaxf(mm_, fv[i][s][fi]);
        mx[tid] = mm_;
    }
    __syncthreads();
    for (int idx = tid; idx < 7168; idx += 256) {
        int i = idx / 3584, s = (idx / 112) % 32, fi = idx % 112;
        int o = i * 32 + s;
        Wout[fi * 64 + o] = fv[i][s][fi] / mx[o];   // layout W[k][o] (f32, for A)
    }
    for (int idx = tid; idx < 8192; idx += 256) {
        int o = idx >> 7, k = idx & 127;
        float val = (k < 112) ? fv[o >> 5][o & 31][k] / mx[o] : 0.f;
        Wtb[idx] = f2bf(val);                      // layout Wt[o][k] bf16, K padded to 128
    }
}

// ---------------- K1b: A[j][k] = sum_o W[j,o] W[k,o] ----------------
__global__ __launch_bounds__(256) void k1b_A(const float* __restrict__ W, float* __restrict__ A)
{
    int idx = blockIdx.x * 256 + threadIdx.x;
    if (idx >= 12544) return;
    int j = idx / 112, k = idx % 112;
    float s = 0.f;
    for (int o = 0; o < 64; ++o) s += W[j * 64 + o] * W[k * 64 + o];
    A[idx] = s;
}

// ---------------- K1c: C[q][dd] ----------------
__global__ __launch_bounds__(256) void k1c_C(const float* __restrict__ A, float* __restrict__ C)
{
    int idx = blockIdx.x * 256 + threadIdx.x;
    if (idx >= 448) return;
    int q = idx / 224, dd = idx % 224;
    int d = dd - 111;
    float s = 0.f;
    for (int k = q; k < 112; k += 2) {
        int jj = k + d;
        if (jj >= 0 && jj < 112) s += A[jj * 112 + k];
    }
    C[idx] = s;
}

// ---------------- K2: MFMA conv + modulus + pooling ----------------
__global__ __launch_bounds__(256) void k2_fwd(
    const float* __restrict__ x, const ushort* __restrict__ Wtb,
    float* __restrict__ out_u, float* __restrict__ out_s)
{
    __shared__ __align__(16) ushort xraw[256];   // bf16 window xp[2*t0 .. 2*t0+255]
    __shared__ float xch[64][65];                // conv result [o][t_local]
    __shared__ float ub[32][65];
    int row = blockIdx.y;                 // n = b*3 + c
    int b = row / 3, c = row % 3;
    int t0 = blockIdx.x * 64;
    const float* xr = x + row * TLEN;
    int tid = threadIdx.x;

    {
        int idx = 2 * t0 + tid;
        float v = (idx < XPLEN) ? fetch_xp(xr, idx) : 0.f;
        xraw[tid] = f2bf(v);
    }
    __syncthreads();

    int l = tid & 63, w = tid >> 6;
    int wm = w >> 1, wn = w & 1;
    int r16 = l & 15, kg = l >> 4;

    float4v acc00 = {0.f, 0.f, 0.f, 0.f};
    float4v acc01 = {0.f, 0.f, 0.f, 0.f};
    float4v acc10 = {0.f, 0.f, 0.f, 0.f};
    float4v acc11 = {0.f, 0.f, 0.f, 0.f};

    const ushort* Wb = Wtb + (wn * 32 + r16) * 128 + kg * 8;
    int abase = 64 * wm + 2 * r16 + 8 * kg;

    union U8 { short8v v; uint u[4]; uint4 q; };

#pragma unroll
    for (int ks = 0; ks < 4; ++ks) {
        U8 b0, b1, a0, a1;
        b0.q = *(const uint4*)(Wb + ks * 32);          // fn=0
        b1.q = *(const uint4*)(Wb + 2048 + ks * 32);   // fn=1 (o+16)
        int e0 = abase + ks * 32;
#pragma unroll
        for (int q = 0; q < 4; ++q) {
            a0.u[q] = *(const uint*)&xraw[e0 + 2 * q];        // fm=0
            a1.u[q] = *(const uint*)&xraw[e0 + 32 + 2 * q];   // fm=1 (t+16)
        }
        acc00 = __builtin_amdgcn_mfma_f32_16x16x32_bf16(a0.v, b0.v, acc00, 0, 0, 0);
        acc01 = __builtin_amdgcn_mfma_f32_16x16x32_bf16(a0.v, b1.v, acc01, 0, 0, 0);
        acc10 = __builtin_amdgcn_mfma_f32_16x16x32_bf16(a1.v, b0.v, acc10, 0, 0, 0);
        acc11 = __builtin_amdgcn_mfma_f32_16x16x32_bf16(a1.v, b1.v, acc11, 0, 0, 0);
    }

    // C/D layout: col(o) = lane&15, row(t) = (lane>>4)*4 + reg
    {
        int ob = wn * 32 + r16;
        int tb = wm * 32 + 4 * kg;
#pragma unroll
        for (int r = 0; r < 4; ++r) {
            xch[ob][tb + r]           = acc00[r];
            xch[ob + 16][tb + r]      = acc01[r];
            xch[ob][tb + 16 + r]      = acc10[r];
            xch[ob + 16][tb + 16 + r] = acc11[r];
        }
    }
    __syncthreads();

    // modulus phase
    int rembase = t0 * 32;
#pragma unroll
    for (int r = 0; r < 8; ++r) {
        int rem = rembase + tid + 256 * r;
        if (rem < REM_MAX) {
            int k = rem / TO;
            int tt = rem - k * TO;
            int sc = rem & 31;
            int tloc = (rem >> 5) - t0;
            float re = xch[sc][tloc];
            float im = xch[sc + 32][tloc];
            float u = sqrtf(re * re + im * im);
            out_u[((b * 32 + k) * 3 + c) * TO + tt] = u;
            ub[sc][tloc] = u;
        }
    }
    __syncthreads();

    int tpbase = t0 >> 2;
#pragma unroll
    for (int r = 0; r < 2; ++r) {
        int idx = tid + 256 * r;
        int sc = idx >> 4, tp = idx & 15;
        if (tpbase + tp < 8192) {
            float sum = ub[sc][tp * 4] + ub[sc][tp * 4 + 1] + ub[sc][tp * 4 + 2] + ub[sc][tp * 4 + 3];
            out_s[(row * 32 + sc) * 8192 + tpbase + tp] = sum * 0.25f;
        }
    }
}

// ---------------- K3: interior inverse + loss (C in LDS, no atomics) ----------------
__global__ __launch_bounds__(256) void k3_interior(
    const float* __restrict__ x, const float* __restrict__ C,
    double* __restrict__ part)
{
    __shared__ __align__(16) float sx[1248];
    __shared__ __align__(16) float Cl[448];
    __shared__ double wred[4];
    int row = blockIdx.y;
    int s0 = 56 + blockIdx.x * 1024;
    const float* xr = x + row * TLEN;
    int tid = threadIdx.x;
    for (int li = tid; li < 1248; li += 256) {
        int pp = s0 - 111 + li;
        pp = (pp < 0) ? (-1 - pp) : pp;
        pp = (pp >= TLEN) ? (2 * TLEN - 1 - pp) : pp;
        sx[li] = xr[pp];
    }
    for (int li = tid; li < 448; li += 256) Cl[li] = C[li];
    __syncthreads();

    int qe = (55 + s0) & 1;
    const float* Ce = Cl + qe * 224;
    const float* Co = Cl + (qe ^ 1) * 224;
    int base = tid * 4;
    float a0 = 0.f, a1 = 0.f, a2 = 0.f, a3 = 0.f;
    float4 cur = *(const float4*)&sx[base];
#pragma unroll 4
    for (int d4 = 0; d4 < 56; ++d4) {
        float4 nxt = *(const float4*)&sx[base + 4 * d4 + 4];
        float4 cev = *(const float4*)&Ce[4 * d4];     // LDS broadcast
        float4 cov = *(const float4*)&Co[4 * d4];     // LDS broadcast
        a0 = fmaf(cur.x, cev.x, a0); a1 = fmaf(cur.y, cov.x, a1); a2 = fmaf(cur.z, cev.x, a2); a3 = fmaf(cur.w, cov.x, a3);
        a0 = fmaf(cur.y, cev.y, a0); a1 = fmaf(cur.z, cov.y, a1); a2 = fmaf(cur.w, cev.y, a2); a3 = fmaf(nxt.x, cov.y, a3);
        a0 = fmaf(cur.z, cev.z, a0); a1 = fmaf(cur.w, cov.z, a1); a2 = fmaf(nxt.x, cev.z, a2); a3 = fmaf(nxt.y, cov.z, a3);
        a0 = fmaf(cur.w, cev.w, a0); a1 = fmaf(nxt.x, cov.w, a1); a2 = fmaf(nxt.y, cev.w, a2); a3 = fmaf(nxt.z, cov.w, a3);
        cur = nxt;
    }

    int sb = s0 + base;
    double lsum = 0.0;
    if (sb + 0 <= 65478) { float d = a0 - sx[base + 111]; lsum += (double)d * d; }
    if (sb + 1 <= 65478) { float d = a1 - sx[base + 112]; lsum += (double)d * d; }
    if (sb + 2 <= 65478) { float d = a2 - sx[base + 113]; lsum += (double)d * d; }
    if (sb + 3 <= 65478) { float d = a3 - sx[base + 114]; lsum += (double)d * d; }
    for (int off = 32; off > 0; off >>= 1) lsum += __shfl_down(lsum, off, 64);
    int w = tid >> 6;
    if ((tid & 63) == 0) wred[w] = lsum;
    __syncthreads();
    if (tid == 0)
        part[row * 64 + blockIdx.x] = wred[0] + wred[1] + wred[2] + wred[3];
}

// ---------------- K4: edge g_xp evals, one wave owns one output (no atomics) ----------------
__global__ __launch_bounds__(256) void k4_edge(
    const float* __restrict__ x, const float* __restrict__ A,
    float* __restrict__ edge)
{
    __shared__ float Al[112][113];
    __shared__ float xpw[240];
    int row = blockIdx.x >> 1;
    int side = blockIdx.x & 1;
    const float* xr = x + row * TLEN;
    int tid = threadIdx.x;

    for (int idx = tid; idx < 12544; idx += 256)
        Al[idx / 112][idx % 112] = A[idx];
    {
        int n_x = side ? 225 : 222;
        int woff = side ? 65423 : 0;
        if (tid < n_x) xpw[tid] = fetch_xp(xr, woff + tid);
    }
    __syncthreads();

    int w = tid >> 6, lane = tid & 63;
    int nS = side ? 57 : 56;
    int woff = side ? 65423 : 0;
    for (int s = w; s < nS; s += 4) {
        float part = 0.f;
#pragma unroll
        for (int half = 0; half < 2; ++half) {
            int i;
            bool has;
            if (!side) { i = half ? (54 - s) : (55 + s); has = half ? (s <= 54) : true; }
            else       { i = half ? (65647 - s) : (65534 + s); has = true; }
            if (has) {
                int klo = max(0, i - 65536);
                int khi = min(111, i);
                int k0 = klo + ((klo ^ i) & 1);
                for (int k = k0; k <= khi; k += 2) {
                    int bi = i - k - woff;
                    part = fmaf(xpw[bi + lane], Al[lane][k], part);
                    if (lane < 48)
                        part = fmaf(xpw[bi + 64 + lane], Al[lane + 64][k], part);
                }
            }
        }
        for (int off = 32; off > 0; off >>= 1) part += __shfl_down(part, off, 64);
        if (lane == 0) edge[row * 128 + side * 64 + s] = part;
    }
}

// ---------------- K5: final reduction ----------------
__global__ __launch_bounds__(256) void k5_final(
    const float* __restrict__ x, const float* __restrict__ edge,
    const double* __restrict__ part, float* __restrict__ out_loss)
{
    __shared__ double red[256];
    double acc = 0.0;
    for (int idx = threadIdx.x; idx < 3072; idx += 256) acc += part[idx];
    for (int idx = threadIdx.x; idx < 5424; idx += 256) {
        int row = idx / 113, r = idx % 113;
        int s, slot;
        if (r < 56) { s = r; slot = row * 128 + r; }
        else        { s = 65479 + (r - 56); slot = row * 128 + 64 + (r - 56); }
        float diff = edge[slot] - x[row * TLEN + s];
        acc += (double)diff * diff;
    }
    red[threadIdx.x] = acc;
    __syncthreads();
    for (int st = 128; st > 0; st >>= 1) {
        if (threadIdx.x < st) red[threadIdx.x] += red[threadIdx.x + st];
        __syncthreads();
    }
    if (threadIdx.x == 0)
        out_loss[0] = (float)(red[0] / 3145728.0);
}

// ---------------- launch ----------------
extern "C" void kernel_launch(void* const* d_in, const int* in_sizes, int n_in,
                              void* d_out, int out_size, void* d_ws, size_t ws_size,
                              hipStream_t stream)
{
    (void)in_sizes; (void)n_in; (void)ws_size;
    const float* x  = (const float*)d_in[0];
    const float* m  = (const float*)d_in[1];
    const float* p  = (const float*)d_in[2];
    const float* sd = (const float*)d_in[3];
    const float* kb = (const float*)d_in[4];
    float* out = (float*)d_out;
    float* ws  = (float*)d_ws;

    float* ws_w    = ws;            // 7168 : W[k][o] f32
    float* ws_C    = ws + 7168;     // 448  : C[q][224]
    float* ws_A    = ws + 7616;     // 12544: A[j][k] -> ends 20160
    float* ws_edge = ws + 20160;    // 6144 : edge inverse values -> ends 26304
    double* ws_part = (double*)(ws + 26304); // 3072 doubles -> ends 32448
    ushort* ws_wtb = (ushort*)(ws + 32448);  // 8192 ushort: Wt[o][k] bf16 padded

    k1_filters<<<1, 256, 0, stream>>>(m, p, sd, kb, ws_w, ws_wtb);
    k1b_A<<<49, 256, 0, stream>>>(ws_w, ws_A);
    k1c_C<<<2, 256, 0, stream>>>(ws_A, ws_C);
    k2_fwd<<<dim3(513, 48), 256, 0, stream>>>(x, ws_wtb, out, out + OU_SIZE);
    k3_interior<<<dim3(64, 48), 256, 0, stream>>>(x, ws_C, ws_part);
    k4_edge<<<96, 256, 0, stream>>>(x, ws_A, ws_edge);
    k5_final<<<1, 256, 0, stream>>>(x, ws_edge, ws_part, out + (out_size - 1));
}